// Round 2
// baseline (110.425 us; speedup 1.0000x reference)
//
#include <hip/hip_runtime.h>

// LePEAttention idx=0 on MI355X — R9.
// R8 (in-register softmax, 32x32x16 swapped QK^T) bought only ~5 us: kernel is NOT
// VALU-bound (compute ~4 us/wave-set) but redundant-fetch bound: 1024 blocks x 144 KB
// = 147 MB f32 (K,V fetched 4x, once per q-split). R9 fuses the 4 q-splits into one
// 1024-thread block (16 waves; wave w -> queries (w>>2)*128+(w&3)*32): staged K/V
// reused by all 512 queries -> 50 MB aggregate reads. Occupancy unchanged (1 blk/CU,
// 4 waves/SIMD, 32.5 KB LDS); inner loop identical to R8; staging redistributed over
// 1024 threads (V re-partitioned as (pair, dim-quarter), stores stay conflict-free).
// qkv f32 [3,8,4096,128]; out f32 [8,4096,128]. 64 windows of S=512, 256 (win,head)
// blocks. mfma_f32_32x32x16_bf16, in-register softmax via cvt_pk + permlane32_swap.

typedef __attribute__((ext_vector_type(8)))  short bf16x8;
typedef __attribute__((ext_vector_type(4)))  float f32x4;
typedef __attribute__((ext_vector_type(16))) float f32x16;
typedef __attribute__((ext_vector_type(4)))  int   i32x4;

#define MFMA32(a, b, c) __builtin_amdgcn_mfma_f32_32x32x16_bf16(a, b, c, 0, 0, 0)

__device__ __forceinline__ unsigned cvtpk(float lo, float hi) {
    unsigned r;
    asm("v_cvt_pk_bf16_f32 %0, %1, %2" : "=v"(r) : "v"(lo), "v"(hi));
    return r;
}
// v_permlane32_swap_b32 vdst, vsrc:  dst' = {dst[0:31], src[0:31]}, src' = {dst[32:63], src[32:63]}
__device__ __forceinline__ void plswap(unsigned& a, unsigned& b) {
    asm("v_permlane32_swap_b32 %0, %1" : "+v"(a), "+v"(b));
}

__global__ __launch_bounds__(1024, 4)
void lepe_attn_r9(const float* __restrict__ qkv, float* __restrict__ out)
{
    __shared__ __align__(16) short    Ks[256 * 32];    // 16 KB, XOR-swizzled 16B blocks
    __shared__ __align__(16) unsigned Vt32[32 * 132];  // 16.5 KB: bf16 [dim][264] pitch, keys packed in pairs

    const int tid  = threadIdx.x;
    const int wave = tid >> 6;          // 0..15
    const int lane = tid & 63;
    const int m31  = lane & 31;
    const int hi   = lane >> 5;

    const int pair = blockIdx.x;        // (win, head)
    const int wi   = pair >> 2;
    const int hd   = pair & 3;
    const int b    = wi >> 3;
    const int wb   = wi & 7;
    const int chead = hd * 32;

    const size_t baseQ = (size_t)b * 524288;
    const size_t baseK = baseQ + 8u * 524288;
    const size_t baseV = baseQ + 16u * 524288;

    // ---- Q B-frags (B[n=q=lane&31][k=d=hi*8+j]), prescaled by SCALE*log2e
    const int qsp = wave >> 2;
    const int wv  = wave & 3;
    const int q0w = qsp * 128 + wv * 32;
    const float QS = 0.17677669529663687f * 1.4426950408889634f;
    bf16x8 qf0, qf1;
    {
        int qg = q0w + m31;
        int lq = (qg >> 3) * 64 + wb * 8 + (qg & 7);
        const float* qp = qkv + baseQ + (size_t)lq * 128 + chead + hi * 8;
        f32x4 qa = *(const f32x4*)qp;          // dims hi*8 + 0..3
        f32x4 qb = *(const f32x4*)(qp + 4);    // dims hi*8 + 4..7
        f32x4 qc = *(const f32x4*)(qp + 16);   // dims 16 + hi*8 + 0..3
        f32x4 qd = *(const f32x4*)(qp + 20);   // dims 16 + hi*8 + 4..7
        i32x4 w0, w1;
        w0[0] = cvtpk(qa[0] * QS, qa[1] * QS);
        w0[1] = cvtpk(qa[2] * QS, qa[3] * QS);
        w0[2] = cvtpk(qb[0] * QS, qb[1] * QS);
        w0[3] = cvtpk(qb[2] * QS, qb[3] * QS);
        w1[0] = cvtpk(qc[0] * QS, qc[1] * QS);
        w1[1] = cvtpk(qc[2] * QS, qc[3] * QS);
        w1[2] = cvtpk(qd[0] * QS, qd[1] * QS);
        w1[3] = cvtpk(qd[2] * QS, qd[3] * QS);
        qf0 = __builtin_bit_cast(bf16x8, w0);
        qf1 = __builtin_bit_cast(bf16x8, w1);
    }

    f32x16 o = (f32x16)0.0f;   // O[q=crow(r,hi)][d=lane&31]
    float lsum = 0.0f;         // per-lane: sum of P[q=lane&31][its 256 keys]

    const short* Vts = (const short*)Vt32;

    for (int stage = 0; stage < 2; ++stage) {
        if (stage) __syncthreads();
        const int keybase = stage * 256;

        // ---- K staging: row-major bf16 [key][32 dims], XOR-swizzled 16B blocks.
        // 1024 threads = 256 rows x 4 parts, one shot.
        {
            int row  = tid >> 2;                 // local key
            int part = tid & 3;                  // 16B dim-block
            int gk   = keybase + row;
            int lk   = (gk >> 3) * 64 + wb * 8 + (gk & 7);
            const float* kp = qkv + baseK + (size_t)lk * 128 + chead + part * 8;
            f32x4 k0 = *(const f32x4*)kp;
            f32x4 k1 = *(const f32x4*)(kp + 4);
            i32x4 kd;
            kd[0] = cvtpk(k0[0], k0[1]);
            kd[1] = cvtpk(k0[2], k0[3]);
            kd[2] = cvtpk(k1[0], k1[1]);
            kd[3] = cvtpk(k1[2], k1[3]);
            *(i32x4*)&Ks[row * 32 + ((part ^ ((row >> 1) & 3)) << 3)] = kd;
        }
        // ---- V staging: transposed bf16 [dim][key], pair-packed dwords.
        // 1024 threads = 128 key-pairs x 8 dim-quarters; within a wave p spans 64
        // consecutive values -> b32 stores 2-way (free), loads 16B segments.
        {
            int p  = tid & 127;                  // key pair
            int qd = tid >> 7;                   // dim quarter 0..7
            int k0g = keybase + 2 * p;
            int l0  = (k0g >> 3) * 64 + wb * 8 + (k0g & 7);    // key 2p+1 is row l0+1
            const float* va = qkv + baseV + (size_t)l0 * 128 + chead + qd * 4;
            f32x4 a  = *(const f32x4*)va;
            f32x4 bbv = *(const f32x4*)(va + 128);
#pragma unroll
            for (int e = 0; e < 4; ++e)
                Vt32[(qd * 4 + e) * 132 + p] = cvtpk(a[e], bbv[e]);
        }
        __syncthreads();

        for (int kb = 0; kb < 256; kb += 32) {
            // K A-frags: A[m=key=kb+m31][k=d slice]; swizzled block read (8 lanes/16B col)
            int row0 = kb + m31;
            int swz  = (row0 >> 1) & 3;
            bf16x8 kfa = *(const bf16x8*)&Ks[row0 * 32 + (((0 + hi) ^ swz) << 3)];  // d  0..15
            bf16x8 kfb = *(const bf16x8*)&Ks[row0 * 32 + (((2 + hi) ^ swz) << 3)];  // d 16..31
            // V B-frags: B[n=d=m31][k=key slice]
            bf16x8 vf0 = *(const bf16x8*)&Vts[m31 * 264 + kb + hi * 8];        // keys kb+0..15
            bf16x8 vf1 = *(const bf16x8*)&Vts[m31 * 264 + kb + 16 + hi * 8];   // keys kb+16..31

            // Swapped QK^T: S[key=crow(r,hi)][q=m31], key_local = (r&3)+8*(r>>2)+4*hi
            f32x16 s = MFMA32(kfa, qf0, (f32x16)0.0f);
            s = MFMA32(kfb, qf1, s);

            float p[16];
#pragma unroll
            for (int r = 0; r < 16; ++r) p[r] = __builtin_amdgcn_exp2f(s[r]);

            float t01 = p[0] + p[1],   t23 = p[2] + p[3];
            float t45 = p[4] + p[5],   t67 = p[6] + p[7];
            float t89 = p[8] + p[9],   tab = p[10] + p[11];
            float tcd = p[12] + p[13], tef = p[14] + p[15];
            lsum += ((t01 + t23) + (t45 + t67)) + ((t89 + tab) + (tcd + tef));

            // PA frags in-register: keys {0,1},{2,3} own; rest via permlane32_swap
            unsigned c0 = cvtpk(p[0], p[1]);    // lo:{0,1}  hi:{4,5}
            unsigned c1 = cvtpk(p[2], p[3]);    // lo:{2,3}  hi:{6,7}
            unsigned c2 = cvtpk(p[4], p[5]);    // lo:{8,9}  hi:{12,13}
            unsigned c3 = cvtpk(p[6], p[7]);    // lo:{10,11} hi:{14,15}
            plswap(c0, c2);                     // c0: lo{0,1}/hi{8,9}   c2: lo{4,5}/hi{12,13}
            plswap(c1, c3);                     // c1: lo{2,3}/hi{10,11} c3: lo{6,7}/hi{14,15}
            i32x4 pw0; pw0[0] = c0; pw0[1] = c1; pw0[2] = c2; pw0[3] = c3;

            unsigned c4 = cvtpk(p[8], p[9]);
            unsigned c5 = cvtpk(p[10], p[11]);
            unsigned c6 = cvtpk(p[12], p[13]);
            unsigned c7 = cvtpk(p[14], p[15]);
            plswap(c4, c6);
            plswap(c5, c7);
            i32x4 pw1; pw1[0] = c4; pw1[1] = c5; pw1[2] = c6; pw1[3] = c7;

            o = MFMA32(__builtin_bit_cast(bf16x8, pw0), vf0, o);
            o = MFMA32(__builtin_bit_cast(bf16x8, pw1), vf1, o);
        }
    }

    // ---- epilogue: combine half-sums across lane^32, normalize, store f32
    float ls  = lsum + __shfl_xor(lsum, 32);
    float inv = 1.0f / ls;
    const size_t baseO = (size_t)b * 524288;
#pragma unroll
    for (int r = 0; r < 16; ++r) {
        int qw = (r & 3) + 8 * (r >> 2) + 4 * hi;     // local q row of o[r]
        float iv = __shfl(inv, qw);                   // inv for q=qw lives at lane qw
        int q  = q0w + qw;
        int lq = (q >> 3) * 64 + wb * 8 + (q & 7);
        out[baseO + (size_t)lq * 128 + chead + m31] = o[r] * iv;
    }
}

extern "C" void kernel_launch(void* const* d_in, const int* in_sizes, int n_in,
                              void* d_out, int out_size, void* d_ws, size_t ws_size,
                              hipStream_t stream) {
    const float* qkv = (const float*)d_in[0];
    float* out = (float*)d_out;
    lepe_attn_r9<<<dim3(256), dim3(1024), 0, stream>>>(qkv, out);
}

// Round 3
// 99.256 us; speedup vs baseline: 1.1125x; 1.1125x over previous
//
#include <hip/hip_runtime.h>

// LePEAttention idx=0 on MI355X — R10.
// R9 (one 1024-thread block per pair) REGRESSED 104->110: redundant K/V fetches were
// L2/L3-absorbed, and the mega-block killed the 4-blocks/CU latency staggering while
// exposing 16-wave barrier cost. R10 reverts to R8's shape (256 thr, 4 blk/CU,
// in-register softmax via swapped 32x32x16 QK^T + cvt_pk + permlane32_swap) and adds
// ONLY an XCD-sibling swizzle: idx = (p&7) + 8*(4*(p>>3)+qsp), bijective, puts all 4
// q-split siblings of a (win,head) pair on the SAME XCD, dispatched consecutively.
// K/V slice (131 KB) is HBM-fetched once, L2-hit 3x (per-XCD set 32x131KB ~ 4MB L2);
// the post-poison L3-cold first touch stops being 4 separate fetches on 4 XCDs.
// qkv f32 [3,8,4096,128]; out f32 [8,4096,128]. 64 windows of S=512, 256 pairs x 4
// q-splits(128q); block 256 = 4 waves x 32 q. LDS 32.5 KB.

typedef __attribute__((ext_vector_type(8)))  short bf16x8;
typedef __attribute__((ext_vector_type(4)))  float f32x4;
typedef __attribute__((ext_vector_type(16))) float f32x16;
typedef __attribute__((ext_vector_type(4)))  int   i32x4;

#define MFMA32(a, b, c) __builtin_amdgcn_mfma_f32_32x32x16_bf16(a, b, c, 0, 0, 0)

__device__ __forceinline__ unsigned cvtpk(float lo, float hi) {
    unsigned r;
    asm("v_cvt_pk_bf16_f32 %0, %1, %2" : "=v"(r) : "v"(lo), "v"(hi));
    return r;
}
// v_permlane32_swap_b32 vdst, vsrc:  dst' = {dst[0:31], src[0:31]}, src' = {dst[32:63], src[32:63]}
__device__ __forceinline__ void plswap(unsigned& a, unsigned& b) {
    asm("v_permlane32_swap_b32 %0, %1" : "+v"(a), "+v"(b));
}

__global__ __launch_bounds__(256, 4)
void lepe_attn_r10(const float* __restrict__ qkv, float* __restrict__ out)
{
    __shared__ __align__(16) short    Ks[256 * 32];    // 16 KB, XOR-swizzled 16B blocks
    __shared__ __align__(16) unsigned Vt32[32 * 132];  // 16.5 KB: bf16 [dim][264] pitch, keys packed in pairs

    const int tid  = threadIdx.x;
    const int wave = tid >> 6;
    const int lane = tid & 63;
    const int m31  = lane & 31;
    const int hi   = lane >> 5;

    // ---- XCD-sibling swizzle: idx = (p&7) + 8*(4*(p>>3)+qsp)
    // All 4 q-splits of pair p share idx%8 -> same XCD, consecutive dispatch order.
    const int idx  = blockIdx.x;
    const int low3 = idx & 7;
    const int t5   = idx >> 3;
    const int qsp  = t5 & 3;
    const int pair = ((t5 >> 2) << 3) | low3;
    const int wi   = pair >> 2;
    const int hd   = pair & 3;
    const int b    = wi >> 3;
    const int wb   = wi & 7;
    const int chead = hd * 32;

    const size_t baseQ = (size_t)b * 524288;
    const size_t baseK = baseQ + 8u * 524288;
    const size_t baseV = baseQ + 16u * 524288;

    // ---- Q B-frags (B[n=q=lane&31][k=d=hi*8+j]), prescaled by SCALE*log2e
    const int q0w = qsp * 128 + wave * 32;
    const float QS = 0.17677669529663687f * 1.4426950408889634f;
    bf16x8 qf0, qf1;
    {
        int qg = q0w + m31;
        int lq = (qg >> 3) * 64 + wb * 8 + (qg & 7);
        const float* qp = qkv + baseQ + (size_t)lq * 128 + chead + hi * 8;
        f32x4 qa = *(const f32x4*)qp;          // dims hi*8 + 0..3
        f32x4 qb = *(const f32x4*)(qp + 4);    // dims hi*8 + 4..7
        f32x4 qc = *(const f32x4*)(qp + 16);   // dims 16 + hi*8 + 0..3
        f32x4 qd = *(const f32x4*)(qp + 20);   // dims 16 + hi*8 + 4..7
        i32x4 w0, w1;
        w0[0] = cvtpk(qa[0] * QS, qa[1] * QS);
        w0[1] = cvtpk(qa[2] * QS, qa[3] * QS);
        w0[2] = cvtpk(qb[0] * QS, qb[1] * QS);
        w0[3] = cvtpk(qb[2] * QS, qb[3] * QS);
        w1[0] = cvtpk(qc[0] * QS, qc[1] * QS);
        w1[1] = cvtpk(qc[2] * QS, qc[3] * QS);
        w1[2] = cvtpk(qd[0] * QS, qd[1] * QS);
        w1[3] = cvtpk(qd[2] * QS, qd[3] * QS);
        qf0 = __builtin_bit_cast(bf16x8, w0);
        qf1 = __builtin_bit_cast(bf16x8, w1);
    }

    f32x16 o = (f32x16)0.0f;   // O[q=crow(r,hi)][d=lane&31]
    float lsum = 0.0f;         // per-lane: sum of P[q=lane&31][its 256 keys]

    const short* Vts = (const short*)Vt32;

    for (int stage = 0; stage < 2; ++stage) {
        if (stage) __syncthreads();
        const int keybase = stage * 256;

        // ---- K staging: row-major bf16 [key][32 dims], XOR-swizzled 16B blocks
#pragma unroll
        for (int i = 0; i < 4; ++i) {
            int chunk = i * 256 + tid;
            int row   = chunk >> 2;              // local key
            int part  = chunk & 3;               // 16B dim-block
            int gk    = keybase + row;
            int lk    = (gk >> 3) * 64 + wb * 8 + (gk & 7);
            const float* kp = qkv + baseK + (size_t)lk * 128 + chead + part * 8;
            f32x4 k0 = *(const f32x4*)kp;
            f32x4 k1 = *(const f32x4*)(kp + 4);
            i32x4 kd;
            kd[0] = cvtpk(k0[0], k0[1]);
            kd[1] = cvtpk(k0[2], k0[3]);
            kd[2] = cvtpk(k1[0], k1[1]);
            kd[3] = cvtpk(k1[2], k1[3]);
            *(i32x4*)&Ks[row * 32 + ((part ^ ((row >> 1) & 3)) << 3)] = kd;
        }
        // ---- V staging: transposed bf16 [dim][key], pair-packed dwords
        {
            int p    = tid >> 1;                 // key pair 0..127
            int half = tid & 1;                  // dim half
            int k0g  = keybase + 2 * p;
            int l0   = (k0g >> 3) * 64 + wb * 8 + (k0g & 7);   // key 2p+1 is row l0+1
            const float* va = qkv + baseV + (size_t)l0 * 128 + chead + half * 16;
            const float* vb = va + 128;
            f32x4 a[4], bb[4];
#pragma unroll
            for (int j = 0; j < 4; ++j) { a[j] = *(const f32x4*)(va + 4 * j); bb[j] = *(const f32x4*)(vb + 4 * j); }
#pragma unroll
            for (int j = 0; j < 4; ++j)
#pragma unroll
                for (int e = 0; e < 4; ++e) {
                    int dim = half * 16 + j * 4 + e;
                    Vt32[dim * 132 + p] = cvtpk(a[j][e], bb[j][e]);
                }
        }
        __syncthreads();

        for (int kb = 0; kb < 256; kb += 32) {
            // K A-frags: A[m=key=kb+m31][k=d slice]; swizzled block read (8 lanes/16B col)
            int row0 = kb + m31;
            int swz  = (row0 >> 1) & 3;
            bf16x8 kfa = *(const bf16x8*)&Ks[row0 * 32 + (((0 + hi) ^ swz) << 3)];  // d  0..15
            bf16x8 kfb = *(const bf16x8*)&Ks[row0 * 32 + (((2 + hi) ^ swz) << 3)];  // d 16..31
            // V B-frags: B[n=d=m31][k=key slice]
            bf16x8 vf0 = *(const bf16x8*)&Vts[m31 * 264 + kb + hi * 8];        // keys kb+0..15
            bf16x8 vf1 = *(const bf16x8*)&Vts[m31 * 264 + kb + 16 + hi * 8];   // keys kb+16..31

            // Swapped QK^T: S[key=crow(r,hi)][q=m31], key_local = (r&3)+8*(r>>2)+4*hi
            f32x16 s = MFMA32(kfa, qf0, (f32x16)0.0f);
            s = MFMA32(kfb, qf1, s);

            float p[16];
#pragma unroll
            for (int r = 0; r < 16; ++r) p[r] = __builtin_amdgcn_exp2f(s[r]);

            float t01 = p[0] + p[1],   t23 = p[2] + p[3];
            float t45 = p[4] + p[5],   t67 = p[6] + p[7];
            float t89 = p[8] + p[9],   tab = p[10] + p[11];
            float tcd = p[12] + p[13], tef = p[14] + p[15];
            lsum += ((t01 + t23) + (t45 + t67)) + ((t89 + tab) + (tcd + tef));

            // PA frags in-register: keys {0,1},{2,3} own; rest via permlane32_swap
            unsigned c0 = cvtpk(p[0], p[1]);    // lo:{0,1}  hi:{4,5}
            unsigned c1 = cvtpk(p[2], p[3]);    // lo:{2,3}  hi:{6,7}
            unsigned c2 = cvtpk(p[4], p[5]);    // lo:{8,9}  hi:{12,13}
            unsigned c3 = cvtpk(p[6], p[7]);    // lo:{10,11} hi:{14,15}
            plswap(c0, c2);                     // c0: lo{0,1}/hi{8,9}   c2: lo{4,5}/hi{12,13}
            plswap(c1, c3);                     // c1: lo{2,3}/hi{10,11} c3: lo{6,7}/hi{14,15}
            i32x4 pw0; pw0[0] = c0; pw0[1] = c1; pw0[2] = c2; pw0[3] = c3;

            unsigned c4 = cvtpk(p[8], p[9]);
            unsigned c5 = cvtpk(p[10], p[11]);
            unsigned c6 = cvtpk(p[12], p[13]);
            unsigned c7 = cvtpk(p[14], p[15]);
            plswap(c4, c6);
            plswap(c5, c7);
            i32x4 pw1; pw1[0] = c4; pw1[1] = c5; pw1[2] = c6; pw1[3] = c7;

            o = MFMA32(__builtin_bit_cast(bf16x8, pw0), vf0, o);
            o = MFMA32(__builtin_bit_cast(bf16x8, pw1), vf1, o);
        }
    }

    // ---- epilogue: combine half-sums across lane^32, normalize, store f32
    float ls  = lsum + __shfl_xor(lsum, 32);
    float inv = 1.0f / ls;
    const size_t baseO = (size_t)b * 524288;
#pragma unroll
    for (int r = 0; r < 16; ++r) {
        int qw = (r & 3) + 8 * (r >> 2) + 4 * hi;     // local q row of o[r]
        float iv = __shfl(inv, qw);                   // inv for q=qw lives at lane qw
        int q  = q0w + qw;
        int lq = (q >> 3) * 64 + wb * 8 + (q & 7);
        out[baseO + (size_t)lq * 128 + chead + m31] = o[r] * iv;
    }
}

extern "C" void kernel_launch(void* const* d_in, const int* in_sizes, int n_in,
                              void* d_out, int out_size, void* d_ws, size_t ws_size,
                              hipStream_t stream) {
    const float* qkv = (const float*)d_in[0];
    float* out = (float*)d_out;
    lepe_attn_r10<<<dim3(1024), dim3(256), 0, stream>>>(qkv, out);
}